// Round 1
// baseline (4266.577 us; speedup 1.0000x reference)
//
#include <hip/hip_runtime.h>
#include <math.h>

#define N_NODES 16384
#define N_EDGES 262144
#define EPSF 1e-8f

// LDS pool layout for edge kernel (floats)
#define XS(e,k)   P[(e)*484 + (k)]          // 0    .. 3872   x vector (480) [s_cat|c0]
#define SC1(e,k)  P[3872 + (e)*164 + (k)]   // 3872 .. 5184   c1 (160)
#define SC2(e,k)  P[5184 + (e)*164 + (k)]   // 5184 .. 6496   c2 (160)
#define SLAT(e,k) P[6496 + (e)*132 + (k)]   // 6496 .. 7552   latents (128)
#define SFR(e,k)  P[7552 + (e)*12  + (k)]   // 7552 .. 7648   frame a,e1,e2 (9)
#define SM0(e,k)  P[7648 + (e)*260 + (k)]   // 7648 .. 9728   m0 (256)
#define SC1O(e,k) P[9728 + (e)*68  + (k)]   // 9728 ..10272   c1o (64)
#define SC2O(e,k) P[10272+ (e)*68  + (k)]   //10272 ..10816   c2o (64)
#define SW(e,k)   P[10816+ (e)*196 + (k)]   //10816 ..12384   w_env (192)
// overlays (valid after B-phase; XS region dead)
#define SSACT(e,k) P[(e)*132 + (k)]         // 0    .. 1056   silu(s_out[:128])
#define SVG(e,k)   P[1056 + (e)*256 + (k)]  // 1056 .. 3104   v_g padded [64][4]

__device__ __forceinline__ float wsum64(float v){
  #pragma unroll
  for (int m=1; m<64; m<<=1) v += __shfl_xor(v, m);
  return v;
}
__device__ __forceinline__ float wsum32(float v){
  #pragma unroll
  for (int m=1; m<32; m<<=1) v += __shfl_xor(v, m);
  return v;
}
__device__ __forceinline__ float sigm(float x){ return 1.0f/(1.0f+expf(-x)); }
__device__ __forceinline__ float silu(float x){ return x/(1.0f+expf(-x)); }

// ---------------- Kernel 1: node separable LN ----------------
__global__ __launch_bounds__(256) void k_node_ln(
    const float* __restrict__ nf, const float* __restrict__ g0,
    const float* __restrict__ b0, const float* __restrict__ g1,
    float* __restrict__ ns_ln, float* __restrict__ nv_ln)
{
  const int tid  = threadIdx.x;
  const int lane = tid & 63;
  const int n    = blockIdx.x*4 + (tid>>6);
  const float* row = nf + (size_t)n*320;

  float s0 = row[lane], s1 = row[64+lane];
  float mu = wsum64(s0+s1) * (1.0f/128.0f);
  float d0 = s0-mu, d1 = s1-mu;
  float var = wsum64(d0*d0+d1*d1) * (1.0f/128.0f);
  float rs = rsqrtf(var + EPSF);
  ns_ln[(size_t)n*128 + lane]      = d0*rs*g0[lane]    + b0[lane];
  ns_ln[(size_t)n*128 + 64+lane]   = d1*rs*g0[64+lane] + b0[64+lane];

  float px = row[128+lane*3+0], py = row[128+lane*3+1], pz = row[128+lane*3+2];
  float vvar = wsum64(px*px+py*py+pz*pz) * (1.0f/192.0f);
  float vsc = rsqrtf(vvar + EPSF) * g1[lane];
  nv_ln[(size_t)n*192 + lane*3+0] = px*vsc;
  nv_ln[(size_t)n*192 + lane*3+1] = py*vsc;
  nv_ln[(size_t)n*192 + lane*3+2] = pz*vsc;
}

// ---------------- Kernel 2: edge message kernel ----------------
__global__ __launch_bounds__(256) void k_edge(
  const float* __restrict__ ef, const float* __restrict__ evec,
  const float* __restrict__ lats,
  const float* __restrict__ g0e, const float* __restrict__ b0e, const float* __restrict__ g1e,
  const float* __restrict__ Wm0, const float* __restrict__ wr, const float* __restrict__ wi,
  const float* __restrict__ Wenv, const float* __restrict__ Wp0, const float* __restrict__ bp0,
  const float* __restrict__ Wpv,
  const int* __restrict__ eidx,
  const float* __restrict__ ns_ln, const float* __restrict__ nv_ln,
  float* __restrict__ sa, float* __restrict__ va)
{
  __shared__ float P[12384];
  __shared__ int EDST[8];
  const int tid = threadIdx.x;
  const int le  = tid >> 5;      // edge-in-block for phase A/B2/B3/C
  const int ln  = tid & 31;
  const int ge  = blockIdx.x*8 + le;

  // ---------------- Phase A: per-edge prep (32 threads / edge) ----------------
  {
    const int src = eidx[ge];
    const int dst = eidx[N_EDGES + ge];
    if (ln==0) EDST[le] = dst;

    // frame (redundant per lane)
    float vx=evec[(size_t)ge*3+0], vy=evec[(size_t)ge*3+1], vz=evec[(size_t)ge*3+2];
    float rn = rsqrtf(vx*vx+vy*vy+vz*vz+EPSF);
    float ax=vx*rn, ay=vy*rn, az=vz*rn;
    float hx, hz;
    if (fabsf(az) < 0.99f) { hx=0.f; hz=1.f; } else { hx=1.f; hz=0.f; }
    float e1x = -hz*ay;
    float e1y = hz*ax - hx*az;
    float e1z = hx*ay;
    float rn1 = rsqrtf(e1x*e1x+e1y*e1y+e1z*e1z+EPSF);
    e1x*=rn1; e1y*=rn1; e1z*=rn1;
    float e2x = ay*e1z - az*e1y;
    float e2y = az*e1x - ax*e1z;
    float e2z = ax*e1y - ay*e1x;
    if (ln==0){
      SFR(le,0)=ax;  SFR(le,1)=ay;  SFR(le,2)=az;
      SFR(le,3)=e1x; SFR(le,4)=e1y; SFR(le,5)=e1z;
      SFR(le,6)=e2x; SFR(le,7)=e2y; SFR(le,8)=e2z;
    }

    // edge scalar LN -> xs[128:192]
    const float* erow = ef + (size_t)ge*160;
    float s0=erow[ln], s1=erow[32+ln];
    float mu = wsum32(s0+s1)*(1.f/64.f);
    float d0=s0-mu, d1=s1-mu;
    float var = wsum32(d0*d0+d1*d1)*(1.f/64.f);
    float rs = rsqrtf(var+EPSF);
    XS(le,128+ln)    = d0*rs*g0e[ln]    + b0e[ln];
    XS(le,160+ln)    = d1*rs*g0e[32+ln] + b0e[32+ln];

    // edge vector LN + projections (channels 64..95 of v_cat)
    float wx=erow[64+ln*3+0], wy=erow[64+ln*3+1], wz=erow[64+ln*3+2];
    float vvar = wsum32(wx*wx+wy*wy+wz*wz)*(1.f/96.f);
    float vsc = rsqrtf(vvar+EPSF)*g1e[ln];
    wx*=vsc; wy*=vsc; wz*=vsc;
    XS(le,320+64+ln) = wx*ax +wy*ay +wz*az;
    SC1(le,64+ln)    = wx*e1x+wy*e1y+wz*e1z;
    SC2(le,64+ln)    = wx*e2x+wy*e2y+wz*e2z;

    // gather node scalars
    const float* nss = ns_ln + (size_t)src*128;
    const float* nsd = ns_ln + (size_t)dst*128;
    #pragma unroll
    for (int q=0;q<4;q++){ int idx=ln+32*q; XS(le,idx)=nss[idx]; XS(le,192+idx)=nsd[idx]; }

    // node vector projections (channels 0..63 and 96..159)
    const float* nvs = nv_ln + (size_t)src*192;
    const float* nvd = nv_ln + (size_t)dst*192;
    #pragma unroll
    for (int q=0;q<2;q++){
      int u = ln+32*q;
      float px=nvs[u*3+0], py=nvs[u*3+1], pz=nvs[u*3+2];
      XS(le,320+u) = px*ax +py*ay +pz*az;
      SC1(le,u)    = px*e1x+py*e1y+pz*e1z;
      SC2(le,u)    = px*e2x+py*e2y+pz*e2z;
      px=nvd[u*3+0]; py=nvd[u*3+1]; pz=nvd[u*3+2];
      XS(le,320+96+u) = px*ax +py*ay +pz*az;
      SC1(le,96+u)    = px*e1x+py*e1y+pz*e1z;
      SC2(le,96+u)    = px*e2x+py*e2y+pz*e2z;
    }

    // latents
    #pragma unroll
    for (int q=0;q<4;q++){ int k=ln+32*q; SLAT(le,k)=lats[(size_t)ge*128+k]; }
  }
  __syncthreads();

  // ---------------- Phase B1: m0 = x @ W_m0  (thread = output column j) ----------------
  {
    float acc[8]={0,0,0,0,0,0,0,0};
    for (int k=0;k<480;k+=4){
      float w0=Wm0[(k+0)*256+tid], w1=Wm0[(k+1)*256+tid];
      float w2=Wm0[(k+2)*256+tid], w3=Wm0[(k+3)*256+tid];
      #pragma unroll
      for (int e=0;e<8;e++){
        float4 xv = *(const float4*)&XS(e,k);
        acc[e] += xv.x*w0 + xv.y*w1 + xv.z*w2 + xv.w*w3;
      }
    }
    #pragma unroll
    for (int e=0;e<8;e++) SM0(e,tid) = acc[e]*0.04564354646f; // 1/sqrt(480)
  }

  // ---------------- Phase B2: c1o/c2o rotation matvecs ----------------
  {
    float a10=0,a11=0,a20=0,a21=0;
    for (int k=0;k<160;k+=4){
      float4 c1v = *(const float4*)&SC1(le,k);
      float4 c2v = *(const float4*)&SC2(le,k);
      #define B2STEP(CK1,CK2,KK) { \
        float wr0=wr[(k+KK)*64+ln], wr1=wr[(k+KK)*64+ln+32]; \
        float wi0=wi[(k+KK)*64+ln], wi1=wi[(k+KK)*64+ln+32]; \
        a10 += (CK1)*wr0 - (CK2)*wi0;  a20 += (CK1)*wi0 + (CK2)*wr0; \
        a11 += (CK1)*wr1 - (CK2)*wi1;  a21 += (CK1)*wi1 + (CK2)*wr1; }
      B2STEP(c1v.x, c2v.x, 0)
      B2STEP(c1v.y, c2v.y, 1)
      B2STEP(c1v.z, c2v.z, 2)
      B2STEP(c1v.w, c2v.w, 3)
      #undef B2STEP
    }
    const float sc = 0.07905694150f; // 1/sqrt(160)
    SC1O(le,ln)    = a10*sc;  SC1O(le,ln+32) = a11*sc;
    SC2O(le,ln)    = a20*sc;  SC2O(le,ln+32) = a21*sc;
  }

  // ---------------- Phase B3: w = latents @ W_env ----------------
  {
    float acc[6]={0,0,0,0,0,0};
    for (int k=0;k<128;k+=4){
      float4 lv = *(const float4*)&SLAT(le,k);
      #pragma unroll
      for (int q=0;q<6;q++){
        acc[q] += lv.x*Wenv[(k+0)*192 + ln + 32*q];
        acc[q] += lv.y*Wenv[(k+1)*192 + ln + 32*q];
        acc[q] += lv.z*Wenv[(k+2)*192 + ln + 32*q];
        acc[q] += lv.w*Wenv[(k+3)*192 + ln + 32*q];
      }
    }
    #pragma unroll
    for (int q=0;q<6;q++) SW(le,ln+32*q) = acc[q]*0.08838834765f; // 1/sqrt(128)
  }
  __syncthreads();

  // ---------------- Phase C1: activations + v_out (overlay writes) ----------------
  {
    float fr[9];
    #pragma unroll
    for (int i=0;i<9;i++) fr[i]=SFR(le,i);
    #pragma unroll
    for (int q=0;q<4;q++){
      int idx=ln+32*q;
      float s=SM0(le,idx);
      SSACT(le,idx) = silu(s);
    }
    #pragma unroll
    for (int q=0;q<2;q++){
      int u = ln+32*q;
      float g   = sigm(SM0(le,128+u));
      float c0o = SM0(le,192+u);
      float c1o = SC1O(le,u), c2o = SC2O(le,u);
      float gx = (c0o*fr[0] + c1o*fr[3] + c2o*fr[6])*g;
      float gy = (c0o*fr[1] + c1o*fr[4] + c2o*fr[7])*g;
      float gz = (c0o*fr[2] + c1o*fr[5] + c2o*fr[8])*g;
      float4 gv = {gx,gy,gz,0.f};
      *(float4*)&SVG(le,u*4) = gv;
    }
  }
  __syncthreads();

  // ---------------- Phase C2: s2 / v2 + scatter ----------------
  {
    const int dst = EDST[le];
    // s2 = silu(s)@Wp0/sqrt(128)+bp0, scaled by w[:128]
    float acc[4]={0,0,0,0};
    for (int k=0;k<128;k+=4){
      float4 sv = *(const float4*)&SSACT(le,k);
      #pragma unroll
      for (int q=0;q<4;q++){
        acc[q] += sv.x*Wp0[(k+0)*128 + ln+32*q];
        acc[q] += sv.y*Wp0[(k+1)*128 + ln+32*q];
        acc[q] += sv.z*Wp0[(k+2)*128 + ln+32*q];
        acc[q] += sv.w*Wp0[(k+3)*128 + ln+32*q];
      }
    }
    #pragma unroll
    for (int q=0;q<4;q++){
      int j=ln+32*q;
      float s2 = (acc[q]*0.08838834765f + bp0[j]) * SW(le,j);
      atomicAdd(&sa[(size_t)dst*128 + j], s2);
    }
    // v2 = vg @ Wpv / 8, scaled by w[128+v]
    float v0x=0,v0y=0,v0z=0, v1x=0,v1y=0,v1z=0;
    for (int u=0;u<64;u++){
      float4 gv = *(const float4*)&SVG(le,u*4);
      float w0 = Wpv[u*64 + ln];
      float w1 = Wpv[u*64 + ln+32];
      v0x += gv.x*w0; v0y += gv.y*w0; v0z += gv.z*w0;
      v1x += gv.x*w1; v1y += gv.y*w1; v1z += gv.z*w1;
    }
    {
      int v=ln;        float sc = 0.125f * SW(le,128+v);
      atomicAdd(&va[(size_t)dst*192 + v*3+0], v0x*sc);
      atomicAdd(&va[(size_t)dst*192 + v*3+1], v0y*sc);
      atomicAdd(&va[(size_t)dst*192 + v*3+2], v0z*sc);
    }
    {
      int v=ln+32;     float sc = 0.125f * SW(le,128+v);
      atomicAdd(&va[(size_t)dst*192 + v*3+0], v1x*sc);
      atomicAdd(&va[(size_t)dst*192 + v*3+1], v1y*sc);
      atomicAdd(&va[(size_t)dst*192 + v*3+2], v1z*sc);
    }
  }
}

// ---------------- Kernel 3: per-node head + residual ----------------
__global__ __launch_bounds__(256) void k_node_out(
  const float* __restrict__ nf, const float* __restrict__ oh,
  const float* __restrict__ Wtp0, const float* __restrict__ Wtp1,
  const float* __restrict__ Wo0, const float* __restrict__ bo0,
  const float* __restrict__ Wov, const float* __restrict__ resp,
  const float* __restrict__ sa, const float* __restrict__ va,
  float* __restrict__ out)
{
  __shared__ float SAB[4][128];
  __shared__ float VAB[4][192];
  __shared__ float S3 [4][128];
  __shared__ float V3 [4][256];
  const int tid=threadIdx.x, lane=tid&63, g=tid>>6;
  const int n = blockIdx.x*4 + g;

  // class index from one-hot
  float cf=0.f;
  #pragma unroll
  for (int j=0;j<16;j++) cf += j*oh[(size_t)n*16+j];
  const int c = (int)(cf+0.5f);

  // stage aggregated messages (apply 1/sqrt(16))
  SAB[g][lane]    = sa[(size_t)n*128+lane]   *0.25f;
  SAB[g][64+lane] = sa[(size_t)n*128+64+lane]*0.25f;
  #pragma unroll
  for (int q=0;q<3;q++) VAB[g][lane+64*q] = va[(size_t)n*192+lane+64*q]*0.25f;
  __syncthreads();

  // t0 (192 outputs, 3 per lane)
  float t00=0.f, t01=0.f, t02=0.f;
  const float* w0c = Wtp0 + (size_t)c*192;
  for (int u=0;u<128;u++){
    float s = SAB[g][u];
    t00 += s * w0c[(size_t)u*3072 + lane];
    t01 += s * w0c[(size_t)u*3072 + lane+64];
    t02 += s * w0c[(size_t)u*3072 + lane+128];
  }
  const float sct0 = 0.02209708691f; // 1/sqrt(2048)
  t00*=sct0; t01*=sct0; t02*=sct0;

  // t1 (v=lane, 3 comps)
  float t1x=0.f,t1y=0.f,t1z=0.f;
  const float* w1c = Wtp1 + (size_t)c*64;
  for (int u=0;u<64;u++){
    float wv = w1c[(size_t)u*1024 + lane];
    t1x += VAB[g][u*3+0]*wv;
    t1y += VAB[g][u*3+1]*wv;
    t1z += VAB[g][u*3+2]*wv;
  }
  t1x*=0.03125f; t1y*=0.03125f; t1z*=0.03125f;

  S3[g][lane]    = silu(t00);
  S3[g][64+lane] = silu(t01);
  float g2 = sigm(t02);
  float4 v3v = {t1x*g2, t1y*g2, t1z*g2, 0.f};
  *(float4*)&V3[g][lane*4] = v3v;
  __syncthreads();

  // s4 = s3 @ Wo0 /sqrt(128) + bo0
  float s40=0.f, s41=0.f;
  for (int k=0;k<128;k++){
    float s3k = S3[g][k];
    s40 += s3k*Wo0[k*128+lane];
    s41 += s3k*Wo0[k*128+64+lane];
  }
  s40 = s40*0.08838834765f + bo0[lane];
  s41 = s41*0.08838834765f + bo0[64+lane];

  // v4 = v3 @ Wov / 8
  float v4x=0.f,v4y=0.f,v4z=0.f;
  for (int u=0;u<64;u++){
    float4 v3u = *(const float4*)&V3[g][u*4];
    float wv = Wov[u*64+lane];
    v4x += v3u.x*wv; v4y += v3u.y*wv; v4z += v3u.z*wv;
  }
  v4x*=0.125f; v4y*=0.125f; v4z*=0.125f;

  // residual mix
  const float r = sigm(resp[0]);
  const float* row = nf + (size_t)n*320;
  float* orow = out + (size_t)n*320;
  orow[lane]      = r*row[lane]      + (1.f-r)*s40;
  orow[64+lane]   = r*row[64+lane]   + (1.f-r)*s41;
  orow[128+lane*3+0] = r*row[128+lane*3+0] + (1.f-r)*v4x;
  orow[128+lane*3+1] = r*row[128+lane*3+1] + (1.f-r)*v4y;
  orow[128+lane*3+2] = r*row[128+lane*3+2] + (1.f-r)*v4z;
}

extern "C" void kernel_launch(void* const* d_in, const int* in_sizes, int n_in,
                              void* d_out, int out_size, void* d_ws, size_t ws_size,
                              hipStream_t stream)
{
  const float* nf   = (const float*)d_in[0];
  const float* ef   = (const float*)d_in[1];
  const float* evec = (const float*)d_in[2];
  const float* lats = (const float*)d_in[3];
  const float* oh   = (const float*)d_in[4];
  const float* g0n  = (const float*)d_in[5];
  const float* b0n  = (const float*)d_in[6];
  const float* g1n  = (const float*)d_in[7];
  const float* g0e  = (const float*)d_in[8];
  const float* b0e  = (const float*)d_in[9];
  const float* g1e  = (const float*)d_in[10];
  const float* Wm0  = (const float*)d_in[11];
  const float* wr   = (const float*)d_in[12];
  const float* wi   = (const float*)d_in[13];
  const float* Wenv = (const float*)d_in[14];
  const float* Wp0  = (const float*)d_in[15];
  const float* bp0  = (const float*)d_in[16];
  const float* Wpv  = (const float*)d_in[17];
  const float* Wtp0 = (const float*)d_in[18];
  const float* Wtp1 = (const float*)d_in[19];
  const float* Wo0  = (const float*)d_in[20];
  const float* bo0  = (const float*)d_in[21];
  const float* Wov  = (const float*)d_in[22];
  const float* resp = (const float*)d_in[23];
  const int*   eidx = (const int*)d_in[24];

  float* ws    = (float*)d_ws;
  float* ns_ln = ws;                           // N*128
  float* nv_ln = ws + (size_t)N_NODES*128;     // N*192
  float* sa    = ws + (size_t)N_NODES*320;     // N*128
  float* va    = ws + (size_t)N_NODES*448;     // N*192

  hipMemsetAsync(sa, 0, (size_t)N_NODES*320*sizeof(float), stream);
  k_node_ln<<<N_NODES/4, 256, 0, stream>>>(nf, g0n, b0n, g1n, ns_ln, nv_ln);
  k_edge<<<N_EDGES/8, 256, 0, stream>>>(ef, evec, lats, g0e, b0e, g1e,
                                        Wm0, wr, wi, Wenv, Wp0, bp0, Wpv,
                                        eidx, ns_ln, nv_ln, sa, va);
  k_node_out<<<N_NODES/4, 256, 0, stream>>>(nf, oh, Wtp0, Wtp1, Wo0, bo0, Wov,
                                            resp, sa, va, (float*)d_out);
}

// Round 2
// 954.636 us; speedup vs baseline: 4.4693x; 4.4693x over previous
//
#include <hip/hip_runtime.h>
#include <math.h>

#define N_NODES 16384
#define N_EDGES 262144
#define EPSF 1e-8f

// ---------------- LDS pool layout (bytes) ----------------
#define OFF_X     0        // bf16 [32][488]  = 31232
#define OFF_C12   31232    // bf16 [32][328]  = 20992
#define OFF_LAT   52224    // bf16 [32][136]  =  8704
#define OFF_FR    60928    // f32  [32][12]   =  1536  (persistent)
#define OFF_EDST  62464    // int  [32]       =   128  (persistent)
#define OFF_WENV  62592    // bf16 [32][200]  = 12800  (persistent from G3)
#define POOL_BYTES 75392
// overlays (after barrier; X/C12/LAT dead)
#define OFF_SACT  0        // bf16 [32][136]  =  8704
#define OFF_GATE  8704     // f32  [32][68]   =  8704
#define OFF_C0O   17408    // f32  [32][68]   =  8704
#define OFF_C1O   31232    // f32  [32][68]   =  8704
#define OFF_C2O   39936    // f32  [32][68]   =  8704
#define OFF_VG    8704     // bf16 [3][32][72]= 13824 (overlays GATE+C0O after they are consumed)

typedef __bf16 bf16x8 __attribute__((ext_vector_type(8)));
typedef float  f32x4  __attribute__((ext_vector_type(4)));

__device__ __forceinline__ f32x4 MFMA16(bf16x8 a, bf16x8 b, f32x4 c){
  return __builtin_amdgcn_mfma_f32_16x16x32_bf16(a, b, c, 0, 0, 0);
}

__device__ __forceinline__ unsigned short f2bf(float x){
  union { float f; unsigned u; } c; c.f = x;
  unsigned u = c.u;
  u += 0x7FFFu + ((u>>16)&1u);
  return (unsigned short)(u>>16);
}
__device__ __forceinline__ float bf2f(unsigned short h){
  union { unsigned u; float f; } c; c.u = ((unsigned)h)<<16;
  return c.f;
}
__device__ __forceinline__ float wsum64(float v){
  #pragma unroll
  for (int m=1; m<64; m<<=1) v += __shfl_xor(v, m);
  return v;
}
__device__ __forceinline__ float wsum32(float v){
  #pragma unroll
  for (int m=1; m<32; m<<=1) v += __shfl_xor(v, m);
  return v;
}
__device__ __forceinline__ float sigm(float x){ return 1.0f/(1.0f+__expf(-x)); }
__device__ __forceinline__ float silu(float x){ return x/(1.0f+__expf(-x)); }

// ---------------- weight pack kernels (B-fragment layout) ----------------
// element (k,n) of row-major [K][N] -> idx = (((k>>5)*N + n)*4 + ((k>>3)&3))*8 + (k&7)
__global__ __launch_bounds__(256) void k_pack(const float* __restrict__ src,
                                              unsigned short* __restrict__ dst,
                                              int K, int N){
  int i = blockIdx.x*256 + threadIdx.x;
  if (i >= K*N) return;
  int k = i / N, n = i - k*N;
  int idx = (((k>>5)*N + n)*4 + ((k>>3)&3))*8 + (k&7);
  dst[idx] = f2bf(src[i]);
}
// Wc[320][128]: [[wr, wi],[-wi, wr]]
__global__ __launch_bounds__(256) void k_pack_wc(const float* __restrict__ wr,
                                                 const float* __restrict__ wi,
                                                 unsigned short* __restrict__ dst){
  int i = blockIdx.x*256 + threadIdx.x;
  if (i >= 320*128) return;
  int k = i >> 7, n = i & 127;
  float v;
  if (k < 160) v = (n < 64) ? wr[k*64 + n]        : wi[k*64 + (n-64)];
  else         v = (n < 64) ? -wi[(k-160)*64 + n] : wr[(k-160)*64 + (n-64)];
  int idx = (((k>>5)*128 + n)*4 + ((k>>3)&3))*8 + (k&7);
  dst[idx] = f2bf(v);
}

// ---------------- Kernel 1: node separable LN ----------------
__global__ __launch_bounds__(256) void k_node_ln(
    const float* __restrict__ nf, const float* __restrict__ g0,
    const float* __restrict__ b0, const float* __restrict__ g1,
    float* __restrict__ ns_ln, float* __restrict__ nv_ln)
{
  const int tid  = threadIdx.x;
  const int lane = tid & 63;
  const int n    = blockIdx.x*4 + (tid>>6);
  const float* row = nf + (size_t)n*320;

  float s0 = row[lane], s1 = row[64+lane];
  float mu = wsum64(s0+s1) * (1.0f/128.0f);
  float d0 = s0-mu, d1 = s1-mu;
  float var = wsum64(d0*d0+d1*d1) * (1.0f/128.0f);
  float rs = rsqrtf(var + EPSF);
  ns_ln[(size_t)n*128 + lane]      = d0*rs*g0[lane]    + b0[lane];
  ns_ln[(size_t)n*128 + 64+lane]   = d1*rs*g0[64+lane] + b0[64+lane];

  float px = row[128+lane*3+0], py = row[128+lane*3+1], pz = row[128+lane*3+2];
  float vvar = wsum64(px*px+py*py+pz*pz) * (1.0f/192.0f);
  float vsc = rsqrtf(vvar + EPSF) * g1[lane];
  nv_ln[(size_t)n*192 + lane*3+0] = px*vsc;
  nv_ln[(size_t)n*192 + lane*3+1] = py*vsc;
  nv_ln[(size_t)n*192 + lane*3+2] = pz*vsc;
}

// ---------------- Kernel 2: edge message kernel (MFMA) ----------------
__global__ __launch_bounds__(256,2) void k_edge(
  const float* __restrict__ ef, const float* __restrict__ evec,
  const float* __restrict__ lats,
  const float* __restrict__ g0e, const float* __restrict__ b0e, const float* __restrict__ g1e,
  const unsigned short* __restrict__ pWm0, const unsigned short* __restrict__ pWc,
  const unsigned short* __restrict__ pWenv, const unsigned short* __restrict__ pWp0,
  const unsigned short* __restrict__ pWpv,
  const float* __restrict__ bp0,
  const int* __restrict__ eidx,
  const float* __restrict__ ns_ln, const float* __restrict__ nv_ln,
  float* __restrict__ sa, float* __restrict__ va)
{
  extern __shared__ unsigned char pool[];
  const int tid = threadIdx.x;
  unsigned short* Xs   = (unsigned short*)(pool + OFF_X);
  unsigned short* C12s = (unsigned short*)(pool + OFF_C12);
  unsigned short* LTs  = (unsigned short*)(pool + OFF_LAT);
  float* FRf = (float*)(pool + OFF_FR);
  int*   EDST = (int*)(pool + OFF_EDST);
  unsigned short* WEs = (unsigned short*)(pool + OFF_WENV);

  // ---------------- Phase A: prep (4 passes of 8 edges, 32 lanes/edge) ----------------
  {
    const int ln = tid & 31;
    for (int eo=0; eo<4; ++eo){
      const int el = eo*8 + (tid>>5);
      const size_t ge = (size_t)blockIdx.x*32 + el;
      const int src = eidx[ge];
      const int dst = eidx[N_EDGES + ge];

      float vx=evec[ge*3+0], vy=evec[ge*3+1], vz=evec[ge*3+2];
      float rn = rsqrtf(vx*vx+vy*vy+vz*vz+EPSF);
      float ax=vx*rn, ay=vy*rn, az=vz*rn;
      float hx, hz;
      if (fabsf(az) < 0.99f){ hx=0.f; hz=1.f; } else { hx=1.f; hz=0.f; }
      float e1x = -hz*ay;
      float e1y = hz*ax - hx*az;
      float e1z = hx*ay;
      float rn1 = rsqrtf(e1x*e1x+e1y*e1y+e1z*e1z+EPSF);
      e1x*=rn1; e1y*=rn1; e1z*=rn1;
      float e2x = ay*e1z - az*e1y;
      float e2y = az*e1x - ax*e1z;
      float e2z = ax*e1y - ay*e1x;
      if (ln==0){
        FRf[el*12+0]=ax;  FRf[el*12+1]=ay;  FRf[el*12+2]=az;
        FRf[el*12+3]=e1x; FRf[el*12+4]=e1y; FRf[el*12+5]=e1z;
        FRf[el*12+6]=e2x; FRf[el*12+7]=e2y; FRf[el*12+8]=e2z;
        EDST[el]=dst;
      }

      const float* erow = ef + ge*160;
      float s0=erow[ln], s1=erow[32+ln];
      float mu = wsum32(s0+s1)*(1.f/64.f);
      float d0=s0-mu, d1=s1-mu;
      float var = wsum32(d0*d0+d1*d1)*(1.f/64.f);
      float rs = rsqrtf(var+EPSF);
      Xs[el*488 + 128+ln] = f2bf(d0*rs*g0e[ln]    + b0e[ln]);
      Xs[el*488 + 160+ln] = f2bf(d1*rs*g0e[32+ln] + b0e[32+ln]);

      float wx=erow[64+ln*3+0], wy=erow[64+ln*3+1], wz=erow[64+ln*3+2];
      float vvar = wsum32(wx*wx+wy*wy+wz*wz)*(1.f/96.f);
      float vsc = rsqrtf(vvar+EPSF)*g1e[ln];
      wx*=vsc; wy*=vsc; wz*=vsc;
      Xs  [el*488 + 320+64+ln]   = f2bf(wx*ax +wy*ay +wz*az);
      C12s[el*328 + 64+ln]       = f2bf(wx*e1x+wy*e1y+wz*e1z);
      C12s[el*328 + 160+64+ln]   = f2bf(wx*e2x+wy*e2y+wz*e2z);

      const float* nss = ns_ln + (size_t)src*128;
      const float* nsd = ns_ln + (size_t)dst*128;
      #pragma unroll
      for (int q=0;q<4;q++){
        int idx=ln+32*q;
        Xs[el*488 + idx]     = f2bf(nss[idx]);
        Xs[el*488 + 192+idx] = f2bf(nsd[idx]);
      }

      const float* nvs = nv_ln + (size_t)src*192;
      const float* nvd = nv_ln + (size_t)dst*192;
      #pragma unroll
      for (int q=0;q<2;q++){
        int u = ln+32*q;
        float px=nvs[u*3+0], py=nvs[u*3+1], pz=nvs[u*3+2];
        Xs  [el*488 + 320+u]     = f2bf(px*ax +py*ay +pz*az);
        C12s[el*328 + u]         = f2bf(px*e1x+py*e1y+pz*e1z);
        C12s[el*328 + 160+u]     = f2bf(px*e2x+py*e2y+pz*e2z);
        px=nvd[u*3+0]; py=nvd[u*3+1]; pz=nvd[u*3+2];
        Xs  [el*488 + 320+96+u]  = f2bf(px*ax +py*ay +pz*az);
        C12s[el*328 + 96+u]      = f2bf(px*e1x+py*e1y+pz*e1z);
        C12s[el*328 + 160+96+u]  = f2bf(px*e2x+py*e2y+pz*e2z);
      }

      #pragma unroll
      for (int q=0;q<4;q++){ int k=ln+32*q; LTs[el*136+k] = f2bf(lats[ge*128+k]); }
    }
  }
  __syncthreads();

  const int wid = tid>>6, l = tid&63;
  const int r15 = l&15, g = l>>4;
  const f32x4 zero4 = {0.f,0.f,0.f,0.f};

  f32x4 acc1[2][4], acc2[2][2], acc3[2][3];
  #pragma unroll
  for (int m=0;m<2;m++){
    #pragma unroll
    for (int n=0;n<4;n++) acc1[m][n]=zero4;
    #pragma unroll
    for (int n=0;n<2;n++) acc2[m][n]=zero4;
    #pragma unroll
    for (int n=0;n<3;n++) acc3[m][n]=zero4;
  }

  // G1: m0 = X[32x480] @ Wm0[480x256]
  for (int kc=0;kc<15;kc++){
    bf16x8 a0 = *(const bf16x8*)&Xs[(    r15)*488 + kc*32 + g*8];
    bf16x8 a1 = *(const bf16x8*)&Xs[(16+ r15)*488 + kc*32 + g*8];
    const unsigned short* bp = pWm0 + ((size_t)(kc*256 + wid*64 + r15)*4 + g)*8;
    #pragma unroll
    for (int n=0;n<4;n++){
      bf16x8 b = *(const bf16x8*)(bp + n*512);
      acc1[0][n] = MFMA16(a0,b,acc1[0][n]);
      acc1[1][n] = MFMA16(a1,b,acc1[1][n]);
    }
  }
  // G2: c12o = C12[32x320] @ Wc[320x128]
  for (int kc=0;kc<10;kc++){
    bf16x8 a0 = *(const bf16x8*)&C12s[(    r15)*328 + kc*32 + g*8];
    bf16x8 a1 = *(const bf16x8*)&C12s[(16+ r15)*328 + kc*32 + g*8];
    const unsigned short* bp = pWc + ((size_t)(kc*128 + wid*32 + r15)*4 + g)*8;
    #pragma unroll
    for (int n=0;n<2;n++){
      bf16x8 b = *(const bf16x8*)(bp + n*512);
      acc2[0][n] = MFMA16(a0,b,acc2[0][n]);
      acc2[1][n] = MFMA16(a1,b,acc2[1][n]);
    }
  }
  // G3: w = LAT[32x128] @ Wenv[128x192]
  for (int kc=0;kc<4;kc++){
    bf16x8 a0 = *(const bf16x8*)&LTs[(    r15)*136 + kc*32 + g*8];
    bf16x8 a1 = *(const bf16x8*)&LTs[(16+ r15)*136 + kc*32 + g*8];
    const unsigned short* bp = pWenv + ((size_t)(kc*192 + wid*48 + r15)*4 + g)*8;
    #pragma unroll
    for (int n=0;n<3;n++){
      bf16x8 b = *(const bf16x8*)(bp + n*512);
      acc3[0][n] = MFMA16(a0,b,acc3[0][n]);
      acc3[1][n] = MFMA16(a1,b,acc3[1][n]);
    }
  }

  // G3 epilogue -> WENV (separate region, safe pre-barrier)
  #pragma unroll
  for (int m=0;m<2;m++)
    #pragma unroll
    for (int n=0;n<3;n++)
      #pragma unroll
      for (int r=0;r<4;r++){
        int e = m*16 + g*4 + r;
        int j = wid*48 + n*16 + r15;
        WEs[e*200 + j] = f2bf(acc3[m][n][r]*0.08838834764831845f);
      }

  __syncthreads();   // all waves done reading X/C12/LAT

  // G1/G2 epilogues -> overlays
  {
    unsigned short* SAs = (unsigned short*)(pool + OFF_SACT);
    float* GAf = (float*)(pool + OFF_GATE);
    float* C0f = (float*)(pool + OFF_C0O);
    #pragma unroll
    for (int m=0;m<2;m++)
      #pragma unroll
      for (int n=0;n<4;n++)
        #pragma unroll
        for (int r=0;r<4;r++){
          int e = m*16 + g*4 + r;
          int j = wid*64 + n*16 + r15;
          float v = acc1[m][n][r]*0.04564354645876384f;  // 1/sqrt(480)
          if (j < 128)      SAs[e*136 + j] = f2bf(silu(v));
          else if (j < 192) GAf[e*68 + (j-128)] = sigm(v);
          else              C0f[e*68 + (j-192)] = v;
        }
    float* C1f = (float*)(pool + OFF_C1O);
    float* C2f = (float*)(pool + OFF_C2O);
    #pragma unroll
    for (int m=0;m<2;m++)
      #pragma unroll
      for (int n=0;n<2;n++)
        #pragma unroll
        for (int r=0;r<4;r++){
          int e = m*16 + g*4 + r;
          int j = wid*32 + n*16 + r15;
          float v = acc2[m][n][r]*0.07905694150420949f;  // 1/sqrt(160)
          if (j < 64) C1f[e*68 + j] = v;
          else        C2f[e*68 + (j-64)] = v;
        }
  }
  __syncthreads();

  // C1: v_g = (c0o*a + c1o*e1 + c2o*e2)*gate  -> VG bf16
  {
    const int e = tid>>3, u0 = (tid&7)*8;
    const float* GAf = (const float*)(pool + OFF_GATE);
    const float* C0f = (const float*)(pool + OFF_C0O);
    const float* C1f = (const float*)(pool + OFF_C1O);
    const float* C2f = (const float*)(pool + OFF_C2O);
    float ax=FRf[e*12+0],  ay=FRf[e*12+1],  az=FRf[e*12+2];
    float b1x=FRf[e*12+3], b1y=FRf[e*12+4], b1z=FRf[e*12+5];
    float b2x=FRf[e*12+6], b2y=FRf[e*12+7], b2z=FRf[e*12+8];
    float vgx[8], vgy[8], vgz[8];
    #pragma unroll
    for (int i=0;i<8;i++){
      int u = u0+i;
      float gt = GAf[e*68+u];
      float c0 = C0f[e*68+u], c1 = C1f[e*68+u], c2 = C2f[e*68+u];
      vgx[i] = (c0*ax + c1*b1x + c2*b2x)*gt;
      vgy[i] = (c0*ay + c1*b1y + c2*b2y)*gt;
      vgz[i] = (c0*az + c1*b1z + c2*b2z)*gt;
    }
    __syncthreads();   // GATE/C0O reads done before VG overlay writes
    unsigned short* VGs = (unsigned short*)(pool + OFF_VG);
    #pragma unroll
    for (int i=0;i<8;i++){
      VGs[0*2304 + e*72 + u0+i] = f2bf(vgx[i]);
      VGs[1*2304 + e*72 + u0+i] = f2bf(vgy[i]);
      VGs[2*2304 + e*72 + u0+i] = f2bf(vgz[i]);
    }
  }
  __syncthreads();

  // G4: s2 = SACT[32x128] @ Wp0[128x128];  G5: v2c = VG[c][32x64] @ Wpv[64x64]
  {
    const unsigned short* SAs = (const unsigned short*)(pool + OFF_SACT);
    const unsigned short* VGs = (const unsigned short*)(pool + OFF_VG);
    f32x4 acc4[2][2], acc5[3][2];
    #pragma unroll
    for (int m=0;m<2;m++){ acc4[m][0]=zero4; acc4[m][1]=zero4; }
    #pragma unroll
    for (int c=0;c<3;c++){ acc5[c][0]=zero4; acc5[c][1]=zero4; }

    for (int kc=0;kc<4;kc++){
      bf16x8 a0 = *(const bf16x8*)&SAs[(    r15)*136 + kc*32 + g*8];
      bf16x8 a1 = *(const bf16x8*)&SAs[(16+ r15)*136 + kc*32 + g*8];
      const unsigned short* bp = pWp0 + ((size_t)(kc*128 + wid*32 + r15)*4 + g)*8;
      #pragma unroll
      for (int n=0;n<2;n++){
        bf16x8 b = *(const bf16x8*)(bp + n*512);
        acc4[0][n] = MFMA16(a0,b,acc4[0][n]);
        acc4[1][n] = MFMA16(a1,b,acc4[1][n]);
      }
    }
    #pragma unroll
    for (int c=0;c<3;c++){
      #pragma unroll
      for (int kc=0;kc<2;kc++){
        bf16x8 a0 = *(const bf16x8*)&VGs[c*2304 + (    r15)*72 + kc*32 + g*8];
        bf16x8 a1 = *(const bf16x8*)&VGs[c*2304 + (16+ r15)*72 + kc*32 + g*8];
        bf16x8 b  = *(const bf16x8*)(pWpv + ((size_t)(kc*64 + wid*16 + r15)*4 + g)*8);
        acc5[c][0] = MFMA16(a0,b,acc5[c][0]);
        acc5[c][1] = MFMA16(a1,b,acc5[c][1]);
      }
    }

    // epilogue: s2 scatter
    #pragma unroll
    for (int m=0;m<2;m++)
      #pragma unroll
      for (int n=0;n<2;n++)
        #pragma unroll
        for (int r=0;r<4;r++){
          int e = m*16 + g*4 + r;
          int j = wid*32 + n*16 + r15;
          float v = acc4[m][n][r]*0.08838834764831845f + bp0[j];  // 1/sqrt(128)
          v *= bf2f(WEs[e*200 + j]);
          atomicAdd(&sa[(size_t)EDST[e]*128 + j], v);
        }
    // epilogue: v2 scatter
    #pragma unroll
    for (int c=0;c<3;c++)
      #pragma unroll
      for (int m=0;m<2;m++)
        #pragma unroll
        for (int r=0;r<4;r++){
          int e = m*16 + g*4 + r;
          int vch = wid*16 + r15;
          float val = acc5[c][m][r]*0.125f * bf2f(WEs[e*200 + 128 + vch]);
          atomicAdd(&va[(size_t)EDST[e]*192 + vch*3 + c], val);
        }
  }
}

// ---------------- Kernel 3: per-node head + residual ----------------
__global__ __launch_bounds__(256) void k_node_out(
  const float* __restrict__ nf, const float* __restrict__ oh,
  const float* __restrict__ Wtp0, const float* __restrict__ Wtp1,
  const float* __restrict__ Wo0, const float* __restrict__ bo0,
  const float* __restrict__ Wov, const float* __restrict__ resp,
  const float* __restrict__ sa, const float* __restrict__ va,
  float* __restrict__ out)
{
  __shared__ float SAB[4][128];
  __shared__ float VAB[4][192];
  __shared__ float S3 [4][128];
  __shared__ float V3 [4][256];
  const int tid=threadIdx.x, lane=tid&63, g=tid>>6;
  const int n = blockIdx.x*4 + g;

  float cf=0.f;
  #pragma unroll
  for (int j=0;j<16;j++) cf += j*oh[(size_t)n*16+j];
  const int c = (int)(cf+0.5f);

  SAB[g][lane]    = sa[(size_t)n*128+lane]   *0.25f;
  SAB[g][64+lane] = sa[(size_t)n*128+64+lane]*0.25f;
  #pragma unroll
  for (int q=0;q<3;q++) VAB[g][lane+64*q] = va[(size_t)n*192+lane+64*q]*0.25f;
  __syncthreads();

  float t00=0.f, t01=0.f, t02=0.f;
  const float* w0c = Wtp0 + (size_t)c*192;
  for (int u=0;u<128;u++){
    float s = SAB[g][u];
    t00 += s * w0c[(size_t)u*3072 + lane];
    t01 += s * w0c[(size_t)u*3072 + lane+64];
    t02 += s * w0c[(size_t)u*3072 + lane+128];
  }
  const float sct0 = 0.02209708691f; // 1/sqrt(2048)
  t00*=sct0; t01*=sct0; t02*=sct0;

  float t1x=0.f,t1y=0.f,t1z=0.f;
  const float* w1c = Wtp1 + (size_t)c*64;
  for (int u=0;u<64;u++){
    float wv = w1c[(size_t)u*1024 + lane];
    t1x += VAB[g][u*3+0]*wv;
    t1y += VAB[g][u*3+1]*wv;
    t1z += VAB[g][u*3+2]*wv;
  }
  t1x*=0.03125f; t1y*=0.03125f; t1z*=0.03125f;

  S3[g][lane]    = silu(t00);
  S3[g][64+lane] = silu(t01);
  float g2 = sigm(t02);
  float4 v3v = {t1x*g2, t1y*g2, t1z*g2, 0.f};
  *(float4*)&V3[g][lane*4] = v3v;
  __syncthreads();

  float s40=0.f, s41=0.f;
  for (int k=0;k<128;k++){
    float s3k = S3[g][k];
    s40 += s3k*Wo0[k*128+lane];
    s41 += s3k*Wo0[k*128+64+lane];
  }
  s40 = s40*0.08838834765f + bo0[lane];
  s41 = s41*0.08838834765f + bo0[64+lane];

  float v4x=0.f,v4y=0.f,v4z=0.f;
  for (int u=0;u<64;u++){
    float4 v3u = *(const float4*)&V3[g][u*4];
    float wv = Wov[u*64+lane];
    v4x += v3u.x*wv; v4y += v3u.y*wv; v4z += v3u.z*wv;
  }
  v4x*=0.125f; v4y*=0.125f; v4z*=0.125f;

  const float r = sigm(resp[0]);
  const float* row = nf + (size_t)n*320;
  float* orow = out + (size_t)n*320;
  orow[lane]      = r*row[lane]      + (1.f-r)*s40;
  orow[64+lane]   = r*row[64+lane]   + (1.f-r)*s41;
  orow[128+lane*3+0] = r*row[128+lane*3+0] + (1.f-r)*v4x;
  orow[128+lane*3+1] = r*row[128+lane*3+1] + (1.f-r)*v4y;
  orow[128+lane*3+2] = r*row[128+lane*3+2] + (1.f-r)*v4z;
}

extern "C" void kernel_launch(void* const* d_in, const int* in_sizes, int n_in,
                              void* d_out, int out_size, void* d_ws, size_t ws_size,
                              hipStream_t stream)
{
  const float* nf   = (const float*)d_in[0];
  const float* ef   = (const float*)d_in[1];
  const float* evec = (const float*)d_in[2];
  const float* lats = (const float*)d_in[3];
  const float* oh   = (const float*)d_in[4];
  const float* g0n  = (const float*)d_in[5];
  const float* b0n  = (const float*)d_in[6];
  const float* g1n  = (const float*)d_in[7];
  const float* g0e  = (const float*)d_in[8];
  const float* b0e  = (const float*)d_in[9];
  const float* g1e  = (const float*)d_in[10];
  const float* Wm0  = (const float*)d_in[11];
  const float* wr   = (const float*)d_in[12];
  const float* wi   = (const float*)d_in[13];
  const float* Wenv = (const float*)d_in[14];
  const float* Wp0  = (const float*)d_in[15];
  const float* bp0  = (const float*)d_in[16];
  const float* Wpv  = (const float*)d_in[17];
  const float* Wtp0 = (const float*)d_in[18];
  const float* Wtp1 = (const float*)d_in[19];
  const float* Wo0  = (const float*)d_in[20];
  const float* bo0  = (const float*)d_in[21];
  const float* Wov  = (const float*)d_in[22];
  const float* resp = (const float*)d_in[23];
  const int*   eidx = (const int*)d_in[24];

  float* ws    = (float*)d_ws;
  float* ns_ln = ws;                           // N*128
  float* nv_ln = ws + (size_t)N_NODES*128;     // N*192
  float* sa    = ws + (size_t)N_NODES*320;     // N*128
  float* va    = ws + (size_t)N_NODES*448;     // N*192
  unsigned short* wpk = (unsigned short*)(ws + (size_t)N_NODES*640);
  unsigned short* pWm0  = wpk;            // 480*256 = 122880
  unsigned short* pWc   = wpk + 122880;   // 320*128 =  40960
  unsigned short* pWenv = wpk + 163840;   // 128*192 =  24576
  unsigned short* pWp0  = wpk + 188416;   // 128*128 =  16384
  unsigned short* pWpv  = wpk + 204800;   //  64*64  =   4096

  hipMemsetAsync(sa, 0, (size_t)N_NODES*320*sizeof(float), stream);
  k_pack<<<(122880+255)/256, 256, 0, stream>>>(Wm0,  pWm0, 480, 256);
  k_pack_wc<<<(40960+255)/256, 256, 0, stream>>>(wr, wi, pWc);
  k_pack<<<(24576+255)/256, 256, 0, stream>>>(Wenv, pWenv, 128, 192);
  k_pack<<<(16384+255)/256, 256, 0, stream>>>(Wp0,  pWp0, 128, 128);
  k_pack<<<(4096+255)/256,  256, 0, stream>>>(Wpv,  pWpv, 64, 64);
  k_node_ln<<<N_NODES/4, 256, 0, stream>>>(nf, g0n, b0n, g1n, ns_ln, nv_ln);
  k_edge<<<N_EDGES/32, 256, POOL_BYTES, stream>>>(ef, evec, lats, g0e, b0e, g1e,
                                                  pWm0, pWc, pWenv, pWp0, pWpv, bp0,
                                                  eidx, ns_ln, nv_ln, sa, va);
  k_node_out<<<N_NODES/4, 256, 0, stream>>>(nf, oh, Wtp0, Wtp1, Wo0, bo0, Wov,
                                            resp, sa, va, (float*)d_out);
}

// Round 3
// 681.518 us; speedup vs baseline: 6.2604x; 1.4007x over previous
//
#include <hip/hip_runtime.h>
#include <math.h>

#define N_NODES 16384
#define N_EDGES 262144
#define EPSF 1e-8f

// ---------------- LDS pool layout (bytes) ----------------
#define OFF_X     0        // bf16 [32][488]  = 31232
#define OFF_C12   31232    // bf16 [32][328]  = 20992
#define OFF_LAT   52224    // bf16 [32][136]  =  8704
#define OFF_FR    60928    // f32  [32][12]   =  1536  (persistent)
#define OFF_EDST  62464    // int  [32]       =   128  (persistent)
#define OFF_WENV  62592    // bf16 [32][200]  = 12800  (persistent from G3)
#define POOL_BYTES 75392
// overlays (after barrier; X/C12/LAT dead)
#define OFF_SACT  0        // bf16 [32][136]  =  8704
#define OFF_GATE  8704     // f32  [32][68]   =  8704
#define OFF_C0O   17408    // f32  [32][68]   =  8704
#define OFF_C1O   31232    // f32  [32][68]   =  8704
#define OFF_C2O   39936    // f32  [32][68]   =  8704
#define OFF_VG    8704     // bf16 [3][32][72]= 13824 (overlays GATE+C0O after consumed)

typedef __bf16 bf16x8 __attribute__((ext_vector_type(8)));
typedef float  f32x4  __attribute__((ext_vector_type(4)));

__device__ __forceinline__ f32x4 MFMA16(bf16x8 a, bf16x8 b, f32x4 c){
  return __builtin_amdgcn_mfma_f32_16x16x32_bf16(a, b, c, 0, 0, 0);
}

__device__ __forceinline__ unsigned short f2bf(float x){
  union { float f; unsigned u; } c; c.f = x;
  unsigned u = c.u;
  u += 0x7FFFu + ((u>>16)&1u);
  return (unsigned short)(u>>16);
}
__device__ __forceinline__ float bf2f(unsigned short h){
  union { unsigned u; float f; } c; c.u = ((unsigned)h)<<16;
  return c.f;
}
__device__ __forceinline__ float wsum64(float v){
  #pragma unroll
  for (int m=1; m<64; m<<=1) v += __shfl_xor(v, m);
  return v;
}
__device__ __forceinline__ float wsum32(float v){
  #pragma unroll
  for (int m=1; m<32; m<<=1) v += __shfl_xor(v, m);
  return v;
}
__device__ __forceinline__ float sigm(float x){ return 1.0f/(1.0f+__expf(-x)); }
__device__ __forceinline__ float silu(float x){ return x/(1.0f+__expf(-x)); }

// ---------------- weight pack kernels (B-fragment layout) ----------------
__global__ __launch_bounds__(256) void k_pack(const float* __restrict__ src,
                                              unsigned short* __restrict__ dst,
                                              int K, int N){
  int i = blockIdx.x*256 + threadIdx.x;
  if (i >= K*N) return;
  int k = i / N, n = i - k*N;
  int idx = (((k>>5)*N + n)*4 + ((k>>3)&3))*8 + (k&7);
  dst[idx] = f2bf(src[i]);
}
__global__ __launch_bounds__(256) void k_pack_wc(const float* __restrict__ wr,
                                                 const float* __restrict__ wi,
                                                 unsigned short* __restrict__ dst){
  int i = blockIdx.x*256 + threadIdx.x;
  if (i >= 320*128) return;
  int k = i >> 7, n = i & 127;
  float v;
  if (k < 160) v = (n < 64) ? wr[k*64 + n]        : wi[k*64 + (n-64)];
  else         v = (n < 64) ? -wi[(k-160)*64 + n] : wr[(k-160)*64 + (n-64)];
  int idx = (((k>>5)*128 + n)*4 + ((k>>3)&3))*8 + (k&7);
  dst[idx] = f2bf(v);
}

// ---------------- CSR build ----------------
__global__ __launch_bounds__(256) void k_hist(const int* __restrict__ eidx, int* __restrict__ cnt){
  int e = blockIdx.x*256 + threadIdx.x;
  if (e < N_EDGES) atomicAdd(&cnt[eidx[N_EDGES+e]], 1);
}
__global__ __launch_bounds__(256) void k_scan(const int* __restrict__ cnt,
                                              int* __restrict__ rowp, int* __restrict__ cursor){
  __shared__ int part[256];
  __shared__ int pref[257];
  const int t = threadIdx.x;
  const int base = t*64;
  int s = 0;
  for (int i=0;i<64;i++) s += cnt[base+i];
  part[t] = s; __syncthreads();
  if (t==0){ int a=0; for (int i=0;i<256;i++){ pref[i]=a; a+=part[i]; } pref[256]=a; }
  __syncthreads();
  int a = pref[t];
  for (int i=0;i<64;i++){ rowp[base+i]=a; cursor[base+i]=a; a += cnt[base+i]; }
  if (t==0) rowp[N_NODES] = pref[256];
}
__global__ __launch_bounds__(256) void k_fill(const int* __restrict__ eidx,
                                              int* __restrict__ cursor, int* __restrict__ perm){
  int e = blockIdx.x*256 + threadIdx.x;
  if (e < N_EDGES){
    int pos = atomicAdd(&cursor[eidx[N_EDGES+e]], 1);
    perm[pos] = e;
  }
}

// ---------------- Kernel 1: node separable LN ----------------
__global__ __launch_bounds__(256) void k_node_ln(
    const float* __restrict__ nf, const float* __restrict__ g0,
    const float* __restrict__ b0, const float* __restrict__ g1,
    float* __restrict__ ns_ln, float* __restrict__ nv_ln)
{
  const int tid  = threadIdx.x;
  const int lane = tid & 63;
  const int n    = blockIdx.x*4 + (tid>>6);
  const float* row = nf + (size_t)n*320;

  float s0 = row[lane], s1 = row[64+lane];
  float mu = wsum64(s0+s1) * (1.0f/128.0f);
  float d0 = s0-mu, d1 = s1-mu;
  float var = wsum64(d0*d0+d1*d1) * (1.0f/128.0f);
  float rs = rsqrtf(var + EPSF);
  ns_ln[(size_t)n*128 + lane]      = d0*rs*g0[lane]    + b0[lane];
  ns_ln[(size_t)n*128 + 64+lane]   = d1*rs*g0[64+lane] + b0[64+lane];

  float px = row[128+lane*3+0], py = row[128+lane*3+1], pz = row[128+lane*3+2];
  float vvar = wsum64(px*px+py*py+pz*pz) * (1.0f/192.0f);
  float vsc = rsqrtf(vvar + EPSF) * g1[lane];
  nv_ln[(size_t)n*192 + lane*3+0] = px*vsc;
  nv_ln[(size_t)n*192 + lane*3+1] = py*vsc;
  nv_ln[(size_t)n*192 + lane*3+2] = pz*vsc;
}

// ---------------- Kernel 2: edge message kernel (MFMA) ----------------
__global__ __launch_bounds__(256,2) void k_edge(
  const float* __restrict__ ef, const float* __restrict__ evec,
  const float* __restrict__ lats,
  const float* __restrict__ g0e, const float* __restrict__ b0e, const float* __restrict__ g1e,
  const unsigned short* __restrict__ pWm0, const unsigned short* __restrict__ pWc,
  const unsigned short* __restrict__ pWenv, const unsigned short* __restrict__ pWp0,
  const unsigned short* __restrict__ pWpv,
  const float* __restrict__ bp0,
  const int* __restrict__ eidx,
  const float* __restrict__ ns_ln, const float* __restrict__ nv_ln,
  float* __restrict__ sa, float* __restrict__ va,
  _Float16* __restrict__ msg, int use_msg)
{
  extern __shared__ unsigned char pool[];
  const int tid = threadIdx.x;
  unsigned short* Xs   = (unsigned short*)(pool + OFF_X);
  unsigned short* C12s = (unsigned short*)(pool + OFF_C12);
  unsigned short* LTs  = (unsigned short*)(pool + OFF_LAT);
  float* FRf = (float*)(pool + OFF_FR);
  int*   EDST = (int*)(pool + OFF_EDST);
  unsigned short* WEs = (unsigned short*)(pool + OFF_WENV);

  // ---------------- Phase A: prep (4 passes of 8 edges, 32 lanes/edge) ----------------
  {
    const int ln = tid & 31;
    for (int eo=0; eo<4; ++eo){
      const int el = eo*8 + (tid>>5);
      const size_t ge = (size_t)blockIdx.x*32 + el;
      const int src = eidx[ge];
      const int dst = eidx[N_EDGES + ge];

      float vx=evec[ge*3+0], vy=evec[ge*3+1], vz=evec[ge*3+2];
      float rn = rsqrtf(vx*vx+vy*vy+vz*vz+EPSF);
      float ax=vx*rn, ay=vy*rn, az=vz*rn;
      float hx, hz;
      if (fabsf(az) < 0.99f){ hx=0.f; hz=1.f; } else { hx=1.f; hz=0.f; }
      float e1x = -hz*ay;
      float e1y = hz*ax - hx*az;
      float e1z = hx*ay;
      float rn1 = rsqrtf(e1x*e1x+e1y*e1y+e1z*e1z+EPSF);
      e1x*=rn1; e1y*=rn1; e1z*=rn1;
      float e2x = ay*e1z - az*e1y;
      float e2y = az*e1x - ax*e1z;
      float e2z = ax*e1y - ay*e1x;
      if (ln==0){
        FRf[el*12+0]=ax;  FRf[el*12+1]=ay;  FRf[el*12+2]=az;
        FRf[el*12+3]=e1x; FRf[el*12+4]=e1y; FRf[el*12+5]=e1z;
        FRf[el*12+6]=e2x; FRf[el*12+7]=e2y; FRf[el*12+8]=e2z;
        EDST[el]=dst;
      }

      const float* erow = ef + ge*160;
      float s0=erow[ln], s1=erow[32+ln];
      float mu = wsum32(s0+s1)*(1.f/64.f);
      float d0=s0-mu, d1=s1-mu;
      float var = wsum32(d0*d0+d1*d1)*(1.f/64.f);
      float rs = rsqrtf(var+EPSF);
      Xs[el*488 + 128+ln] = f2bf(d0*rs*g0e[ln]    + b0e[ln]);
      Xs[el*488 + 160+ln] = f2bf(d1*rs*g0e[32+ln] + b0e[32+ln]);

      float wx=erow[64+ln*3+0], wy=erow[64+ln*3+1], wz=erow[64+ln*3+2];
      float vvar = wsum32(wx*wx+wy*wy+wz*wz)*(1.f/96.f);
      float vsc = rsqrtf(vvar+EPSF)*g1e[ln];
      wx*=vsc; wy*=vsc; wz*=vsc;
      Xs  [el*488 + 320+64+ln]   = f2bf(wx*ax +wy*ay +wz*az);
      C12s[el*328 + 64+ln]       = f2bf(wx*e1x+wy*e1y+wz*e1z);
      C12s[el*328 + 160+64+ln]   = f2bf(wx*e2x+wy*e2y+wz*e2z);

      const float* nss = ns_ln + (size_t)src*128;
      const float* nsd = ns_ln + (size_t)dst*128;
      #pragma unroll
      for (int q=0;q<4;q++){
        int idx=ln+32*q;
        Xs[el*488 + idx]     = f2bf(nss[idx]);
        Xs[el*488 + 192+idx] = f2bf(nsd[idx]);
      }

      const float* nvs = nv_ln + (size_t)src*192;
      const float* nvd = nv_ln + (size_t)dst*192;
      #pragma unroll
      for (int q=0;q<2;q++){
        int u = ln+32*q;
        float px=nvs[u*3+0], py=nvs[u*3+1], pz=nvs[u*3+2];
        Xs  [el*488 + 320+u]     = f2bf(px*ax +py*ay +pz*az);
        C12s[el*328 + u]         = f2bf(px*e1x+py*e1y+pz*e1z);
        C12s[el*328 + 160+u]     = f2bf(px*e2x+py*e2y+pz*e2z);
        px=nvd[u*3+0]; py=nvd[u*3+1]; pz=nvd[u*3+2];
        Xs  [el*488 + 320+96+u]  = f2bf(px*ax +py*ay +pz*az);
        C12s[el*328 + 96+u]      = f2bf(px*e1x+py*e1y+pz*e1z);
        C12s[el*328 + 160+96+u]  = f2bf(px*e2x+py*e2y+pz*e2z);
      }

      #pragma unroll
      for (int q=0;q<4;q++){ int k=ln+32*q; LTs[el*136+k] = f2bf(lats[ge*128+k]); }
    }
  }
  __syncthreads();

  const int wid = tid>>6, l = tid&63;
  const int r15 = l&15, g = l>>4;
  const f32x4 zero4 = {0.f,0.f,0.f,0.f};

  f32x4 acc1[2][4], acc2[2][2], acc3[2][3];
  #pragma unroll
  for (int m=0;m<2;m++){
    #pragma unroll
    for (int n=0;n<4;n++) acc1[m][n]=zero4;
    #pragma unroll
    for (int n=0;n<2;n++) acc2[m][n]=zero4;
    #pragma unroll
    for (int n=0;n<3;n++) acc3[m][n]=zero4;
  }

  // G1: m0 = X[32x480] @ Wm0[480x256]
  for (int kc=0;kc<15;kc++){
    bf16x8 a0 = *(const bf16x8*)&Xs[(    r15)*488 + kc*32 + g*8];
    bf16x8 a1 = *(const bf16x8*)&Xs[(16+ r15)*488 + kc*32 + g*8];
    const unsigned short* bp = pWm0 + ((size_t)(kc*256 + wid*64 + r15)*4 + g)*8;
    #pragma unroll
    for (int n=0;n<4;n++){
      bf16x8 b = *(const bf16x8*)(bp + n*512);
      acc1[0][n] = MFMA16(a0,b,acc1[0][n]);
      acc1[1][n] = MFMA16(a1,b,acc1[1][n]);
    }
  }
  // G2: c12o = C12[32x320] @ Wc[320x128]
  for (int kc=0;kc<10;kc++){
    bf16x8 a0 = *(const bf16x8*)&C12s[(    r15)*328 + kc*32 + g*8];
    bf16x8 a1 = *(const bf16x8*)&C12s[(16+ r15)*328 + kc*32 + g*8];
    const unsigned short* bp = pWc + ((size_t)(kc*128 + wid*32 + r15)*4 + g)*8;
    #pragma unroll
    for (int n=0;n<2;n++){
      bf16x8 b = *(const bf16x8*)(bp + n*512);
      acc2[0][n] = MFMA16(a0,b,acc2[0][n]);
      acc2[1][n] = MFMA16(a1,b,acc2[1][n]);
    }
  }
  // G3: w = LAT[32x128] @ Wenv[128x192]
  for (int kc=0;kc<4;kc++){
    bf16x8 a0 = *(const bf16x8*)&LTs[(    r15)*136 + kc*32 + g*8];
    bf16x8 a1 = *(const bf16x8*)&LTs[(16+ r15)*136 + kc*32 + g*8];
    const unsigned short* bp = pWenv + ((size_t)(kc*192 + wid*48 + r15)*4 + g)*8;
    #pragma unroll
    for (int n=0;n<3;n++){
      bf16x8 b = *(const bf16x8*)(bp + n*512);
      acc3[0][n] = MFMA16(a0,b,acc3[0][n]);
      acc3[1][n] = MFMA16(a1,b,acc3[1][n]);
    }
  }

  // G3 epilogue -> WENV
  #pragma unroll
  for (int m=0;m<2;m++)
    #pragma unroll
    for (int n=0;n<3;n++)
      #pragma unroll
      for (int r=0;r<4;r++){
        int e = m*16 + g*4 + r;
        int j = wid*48 + n*16 + r15;
        WEs[e*200 + j] = f2bf(acc3[m][n][r]*0.08838834764831845f);
      }

  __syncthreads();

  // G1/G2 epilogues -> overlays
  {
    unsigned short* SAs = (unsigned short*)(pool + OFF_SACT);
    float* GAf = (float*)(pool + OFF_GATE);
    float* C0f = (float*)(pool + OFF_C0O);
    #pragma unroll
    for (int m=0;m<2;m++)
      #pragma unroll
      for (int n=0;n<4;n++)
        #pragma unroll
        for (int r=0;r<4;r++){
          int e = m*16 + g*4 + r;
          int j = wid*64 + n*16 + r15;
          float v = acc1[m][n][r]*0.04564354645876384f;  // 1/sqrt(480)
          if (j < 128)      SAs[e*136 + j] = f2bf(silu(v));
          else if (j < 192) GAf[e*68 + (j-128)] = sigm(v);
          else              C0f[e*68 + (j-192)] = v;
        }
    float* C1f = (float*)(pool + OFF_C1O);
    float* C2f = (float*)(pool + OFF_C2O);
    #pragma unroll
    for (int m=0;m<2;m++)
      #pragma unroll
      for (int n=0;n<2;n++)
        #pragma unroll
        for (int r=0;r<4;r++){
          int e = m*16 + g*4 + r;
          int j = wid*32 + n*16 + r15;
          float v = acc2[m][n][r]*0.07905694150420949f;  // 1/sqrt(160)
          if (j < 64) C1f[e*68 + j] = v;
          else        C2f[e*68 + (j-64)] = v;
        }
  }
  __syncthreads();

  // C1: v_g = (c0o*a + c1o*e1 + c2o*e2)*gate -> VG bf16
  {
    const int e = tid>>3, u0 = (tid&7)*8;
    const float* GAf = (const float*)(pool + OFF_GATE);
    const float* C0f = (const float*)(pool + OFF_C0O);
    const float* C1f = (const float*)(pool + OFF_C1O);
    const float* C2f = (const float*)(pool + OFF_C2O);
    float ax=FRf[e*12+0],  ay=FRf[e*12+1],  az=FRf[e*12+2];
    float b1x=FRf[e*12+3], b1y=FRf[e*12+4], b1z=FRf[e*12+5];
    float b2x=FRf[e*12+6], b2y=FRf[e*12+7], b2z=FRf[e*12+8];
    float vgx[8], vgy[8], vgz[8];
    #pragma unroll
    for (int i=0;i<8;i++){
      int u = u0+i;
      float gt = GAf[e*68+u];
      float c0 = C0f[e*68+u], c1 = C1f[e*68+u], c2 = C2f[e*68+u];
      vgx[i] = (c0*ax + c1*b1x + c2*b2x)*gt;
      vgy[i] = (c0*ay + c1*b1y + c2*b2y)*gt;
      vgz[i] = (c0*az + c1*b1z + c2*b2z)*gt;
    }
    __syncthreads();
    unsigned short* VGs = (unsigned short*)(pool + OFF_VG);
    #pragma unroll
    for (int i=0;i<8;i++){
      VGs[0*2304 + e*72 + u0+i] = f2bf(vgx[i]);
      VGs[1*2304 + e*72 + u0+i] = f2bf(vgy[i]);
      VGs[2*2304 + e*72 + u0+i] = f2bf(vgz[i]);
    }
  }
  __syncthreads();

  // G4: s2 = SACT @ Wp0 ; G5: v2c = VG[c] @ Wpv ; epilogue scatter/store
  {
    const unsigned short* SAs = (const unsigned short*)(pool + OFF_SACT);
    const unsigned short* VGs = (const unsigned short*)(pool + OFF_VG);
    f32x4 acc4[2][2], acc5[3][2];
    #pragma unroll
    for (int m=0;m<2;m++){ acc4[m][0]=zero4; acc4[m][1]=zero4; }
    #pragma unroll
    for (int c=0;c<3;c++){ acc5[c][0]=zero4; acc5[c][1]=zero4; }

    for (int kc=0;kc<4;kc++){
      bf16x8 a0 = *(const bf16x8*)&SAs[(    r15)*136 + kc*32 + g*8];
      bf16x8 a1 = *(const bf16x8*)&SAs[(16+ r15)*136 + kc*32 + g*8];
      const unsigned short* bp = pWp0 + ((size_t)(kc*128 + wid*32 + r15)*4 + g)*8;
      #pragma unroll
      for (int n=0;n<2;n++){
        bf16x8 b = *(const bf16x8*)(bp + n*512);
        acc4[0][n] = MFMA16(a0,b,acc4[0][n]);
        acc4[1][n] = MFMA16(a1,b,acc4[1][n]);
      }
    }
    #pragma unroll
    for (int c=0;c<3;c++){
      #pragma unroll
      for (int kc=0;kc<2;kc++){
        bf16x8 a0 = *(const bf16x8*)&VGs[c*2304 + (    r15)*72 + kc*32 + g*8];
        bf16x8 a1 = *(const bf16x8*)&VGs[c*2304 + (16+ r15)*72 + kc*32 + g*8];
        bf16x8 b  = *(const bf16x8*)(pWpv + ((size_t)(kc*64 + wid*16 + r15)*4 + g)*8);
        acc5[c][0] = MFMA16(a0,b,acc5[c][0]);
        acc5[c][1] = MFMA16(a1,b,acc5[c][1]);
      }
    }

    if (use_msg){
      const size_t gebase = (size_t)blockIdx.x*32;
      #pragma unroll
      for (int m=0;m<2;m++)
        #pragma unroll
        for (int n=0;n<2;n++)
          #pragma unroll
          for (int r=0;r<4;r++){
            int e = m*16 + g*4 + r;
            int j = wid*32 + n*16 + r15;
            float v = acc4[m][n][r]*0.08838834764831845f + bp0[j];
            v *= bf2f(WEs[e*200 + j]);
            msg[(gebase+e)*320 + j] = (_Float16)v;
          }
      #pragma unroll
      for (int c=0;c<3;c++)
        #pragma unroll
        for (int m=0;m<2;m++)
          #pragma unroll
          for (int r=0;r<4;r++){
            int e = m*16 + g*4 + r;
            int vch = wid*16 + r15;
            float val = acc5[c][m][r]*0.125f * bf2f(WEs[e*200 + 128 + vch]);
            msg[(gebase+e)*320 + 128 + c*64 + vch] = (_Float16)val;
          }
    } else {
      #pragma unroll
      for (int m=0;m<2;m++)
        #pragma unroll
        for (int n=0;n<2;n++)
          #pragma unroll
          for (int r=0;r<4;r++){
            int e = m*16 + g*4 + r;
            int j = wid*32 + n*16 + r15;
            float v = acc4[m][n][r]*0.08838834764831845f + bp0[j];
            v *= bf2f(WEs[e*200 + j]);
            atomicAdd(&sa[(size_t)EDST[e]*128 + j], v);
          }
      #pragma unroll
      for (int c=0;c<3;c++)
        #pragma unroll
        for (int m=0;m<2;m++)
          #pragma unroll
          for (int r=0;r<4;r++){
            int e = m*16 + g*4 + r;
            int vch = wid*16 + r15;
            float val = acc5[c][m][r]*0.125f * bf2f(WEs[e*200 + 128 + vch]);
            atomicAdd(&va[(size_t)EDST[e]*192 + vch*3 + c], val);
          }
    }
  }
}

// ---------------- Kernel 3: per-node aggregate + head + residual ----------------
__global__ __launch_bounds__(256) void k_node_out(
  const float* __restrict__ nf, const float* __restrict__ oh,
  const float* __restrict__ Wtp0, const float* __restrict__ Wtp1,
  const float* __restrict__ Wo0, const float* __restrict__ bo0,
  const float* __restrict__ Wov, const float* __restrict__ resp,
  const float* __restrict__ sa, const float* __restrict__ va,
  const _Float16* __restrict__ msg, const int* __restrict__ rowp,
  const int* __restrict__ perm, int use_msg,
  float* __restrict__ out)
{
  __shared__ float SAB[4][128];
  __shared__ float VX[4][64], VY[4][64], VZ[4][64];
  __shared__ float S3 [4][128];
  __shared__ float V3 [4][256];
  const int tid=threadIdx.x, lane=tid&63, g=tid>>6;
  const int n = blockIdx.x*4 + g;

  float cf=0.f;
  #pragma unroll
  for (int j=0;j<16;j++) cf += j*oh[(size_t)n*16+j];
  const int c = (int)(cf+0.5f);

  if (use_msg){
    float a0=0.f,a1=0.f,vx=0.f,vy=0.f,vz=0.f;
    const int beg = rowp[n], end = rowp[n+1];
    for (int i=beg;i<end;++i){
      const _Float16* mr = msg + (size_t)perm[i]*320;
      a0 += (float)mr[lane];
      a1 += (float)mr[64+lane];
      vx += (float)mr[128+lane];
      vy += (float)mr[192+lane];
      vz += (float)mr[256+lane];
    }
    SAB[g][lane]    = a0*0.25f;
    SAB[g][64+lane] = a1*0.25f;
    VX[g][lane]=vx*0.25f; VY[g][lane]=vy*0.25f; VZ[g][lane]=vz*0.25f;
  } else {
    SAB[g][lane]    = sa[(size_t)n*128+lane]   *0.25f;
    SAB[g][64+lane] = sa[(size_t)n*128+64+lane]*0.25f;
    VX[g][lane] = va[(size_t)n*192+lane*3+0]*0.25f;
    VY[g][lane] = va[(size_t)n*192+lane*3+1]*0.25f;
    VZ[g][lane] = va[(size_t)n*192+lane*3+2]*0.25f;
  }
  __syncthreads();

  float t00=0.f, t01=0.f, t02=0.f;
  const float* w0c = Wtp0 + (size_t)c*192;
  for (int u=0;u<128;u++){
    float s = SAB[g][u];
    t00 += s * w0c[(size_t)u*3072 + lane];
    t01 += s * w0c[(size_t)u*3072 + lane+64];
    t02 += s * w0c[(size_t)u*3072 + lane+128];
  }
  const float sct0 = 0.02209708691f; // 1/sqrt(2048)
  t00*=sct0; t01*=sct0; t02*=sct0;

  float t1x=0.f,t1y=0.f,t1z=0.f;
  const float* w1c = Wtp1 + (size_t)c*64;
  for (int u=0;u<64;u++){
    float wv = w1c[(size_t)u*1024 + lane];
    t1x += VX[g][u]*wv;
    t1y += VY[g][u]*wv;
    t1z += VZ[g][u]*wv;
  }
  t1x*=0.03125f; t1y*=0.03125f; t1z*=0.03125f;

  S3[g][lane]    = silu(t00);
  S3[g][64+lane] = silu(t01);
  float g2 = sigm(t02);
  float4 v3v = {t1x*g2, t1y*g2, t1z*g2, 0.f};
  *(float4*)&V3[g][lane*4] = v3v;
  __syncthreads();

  float s40=0.f, s41=0.f;
  for (int k=0;k<128;k++){
    float s3k = S3[g][k];
    s40 += s3k*Wo0[k*128+lane];
    s41 += s3k*Wo0[k*128+64+lane];
  }
  s40 = s40*0.08838834765f + bo0[lane];
  s41 = s41*0.08838834765f + bo0[64+lane];

  float v4x=0.f,v4y=0.f,v4z=0.f;
  for (int u=0;u<64;u++){
    float4 v3u = *(const float4*)&V3[g][u*4];
    float wv = Wov[u*64+lane];
    v4x += v3u.x*wv; v4y += v3u.y*wv; v4z += v3u.z*wv;
  }
  v4x*=0.125f; v4y*=0.125f; v4z*=0.125f;

  const float r = sigm(resp[0]);
  const float* row = nf + (size_t)n*320;
  float* orow = out + (size_t)n*320;
  orow[lane]      = r*row[lane]      + (1.f-r)*s40;
  orow[64+lane]   = r*row[64+lane]   + (1.f-r)*s41;
  orow[128+lane*3+0] = r*row[128+lane*3+0] + (1.f-r)*v4x;
  orow[128+lane*3+1] = r*row[128+lane*3+1] + (1.f-r)*v4y;
  orow[128+lane*3+2] = r*row[128+lane*3+2] + (1.f-r)*v4z;
}

extern "C" void kernel_launch(void* const* d_in, const int* in_sizes, int n_in,
                              void* d_out, int out_size, void* d_ws, size_t ws_size,
                              hipStream_t stream)
{
  const float* nf   = (const float*)d_in[0];
  const float* ef   = (const float*)d_in[1];
  const float* evec = (const float*)d_in[2];
  const float* lats = (const float*)d_in[3];
  const float* oh   = (const float*)d_in[4];
  const float* g0n  = (const float*)d_in[5];
  const float* b0n  = (const float*)d_in[6];
  const float* g1n  = (const float*)d_in[7];
  const float* g0e  = (const float*)d_in[8];
  const float* b0e  = (const float*)d_in[9];
  const float* g1e  = (const float*)d_in[10];
  const float* Wm0  = (const float*)d_in[11];
  const float* wr   = (const float*)d_in[12];
  const float* wi   = (const float*)d_in[13];
  const float* Wenv = (const float*)d_in[14];
  const float* Wp0  = (const float*)d_in[15];
  const float* bp0  = (const float*)d_in[16];
  const float* Wpv  = (const float*)d_in[17];
  const float* Wtp0 = (const float*)d_in[18];
  const float* Wtp1 = (const float*)d_in[19];
  const float* Wo0  = (const float*)d_in[20];
  const float* bo0  = (const float*)d_in[21];
  const float* Wov  = (const float*)d_in[22];
  const float* resp = (const float*)d_in[23];
  const int*   eidx = (const int*)d_in[24];

  float* ws    = (float*)d_ws;
  float* ns_ln = ws;                            // N*128
  float* nv_ln = ws + (size_t)N_NODES*128;      // N*192
  float* sa    = ws + (size_t)N_NODES*320;      // N*128 (atomic mode)
  float* va    = ws + (size_t)N_NODES*448;      // N*192 (atomic mode)
  unsigned short* wpk = (unsigned short*)(ws + (size_t)N_NODES*640);
  unsigned short* pWm0  = wpk;            // 480*256
  unsigned short* pWc   = wpk + 122880;   // 320*128
  unsigned short* pWenv = wpk + 163840;   // 128*192
  unsigned short* pWp0  = wpk + 188416;   // 128*128
  unsigned short* pWpv  = wpk + 204800;   //  64*64
  int* ibuf   = (int*)(ws + (size_t)N_NODES*640 + 104448);
  int* cnt    = ibuf;                  // 16384
  int* rowp   = ibuf + 16384;          // 16385
  int* cursor = ibuf + 32769;          // 16384
  int* perm   = ibuf + 49153;          // 262144
  _Float16* msg = (_Float16*)(ws + (size_t)N_NODES*640 + 104448 + 311304);

  const size_t need = ((size_t)N_NODES*640 + 104448 + 311304)*4 + (size_t)N_EDGES*320*2;
  const int use_msg = (ws_size >= need) ? 1 : 0;

  k_pack<<<(122880+255)/256, 256, 0, stream>>>(Wm0,  pWm0, 480, 256);
  k_pack_wc<<<(40960+255)/256, 256, 0, stream>>>(wr, wi, pWc);
  k_pack<<<(24576+255)/256, 256, 0, stream>>>(Wenv, pWenv, 128, 192);
  k_pack<<<(16384+255)/256, 256, 0, stream>>>(Wp0,  pWp0, 128, 128);
  k_pack<<<(4096+255)/256,  256, 0, stream>>>(Wpv,  pWpv, 64, 64);
  k_node_ln<<<N_NODES/4, 256, 0, stream>>>(nf, g0n, b0n, g1n, ns_ln, nv_ln);

  if (use_msg){
    hipMemsetAsync(cnt, 0, N_NODES*sizeof(int), stream);
    k_hist<<<(N_EDGES+255)/256, 256, 0, stream>>>(eidx, cnt);
    k_scan<<<1, 256, 0, stream>>>(cnt, rowp, cursor);
    k_fill<<<(N_EDGES+255)/256, 256, 0, stream>>>(eidx, cursor, perm);
  } else {
    hipMemsetAsync(sa, 0, (size_t)N_NODES*320*sizeof(float), stream);
  }

  k_edge<<<N_EDGES/32, 256, POOL_BYTES, stream>>>(ef, evec, lats, g0e, b0e, g1e,
                                                  pWm0, pWc, pWenv, pWp0, pWpv, bp0,
                                                  eidx, ns_ln, nv_ln, sa, va, msg, use_msg);
  k_node_out<<<N_NODES/4, 256, 0, stream>>>(nf, oh, Wtp0, Wtp1, Wo0, bo0, Wov,
                                            resp, sa, va, msg, rowp, perm, use_msg,
                                            (float*)d_out);
}